// Round 4
// baseline (177.983 us; speedup 1.0000x reference)
//
#include <hip/hip_runtime.h>

// Smoother: out = max(pred, (reflect-pad moving-sum(K=501) + bias)/K)
// pred: [B=8, T=16384, C=128] fp32.
// Round 4: scalar fp32 lanes (wave = 64 of 128 channels -> 2x waves = 2/SIMD),
// init unrolled x16 with 16 independent accumulators (16 loads in flight),
// slide unrolled x8 (24 loads in flight), XCD swizzle (batch b -> XCD b),
// nontemporal stores.

constexpr int B  = 8;
constexpr int T  = 16384;
constexpr int C  = 128;
constexpr int K  = 501;
constexpr int Pp = 250;
constexpr int TT = 128;    // outputs per wave
constexpr int BLOCK = 256; // 4 waves: 2 consecutive t-tiles x 2 channel-halves

__device__ __forceinline__ int ridx(int j) {
    j = (j < 0) ? -j : j;
    return (j >= T) ? (2 * T - 2 - j) : j;
}

__global__ __launch_bounds__(BLOCK) void smoother_kernel(
    const float* __restrict__ pred, const float* __restrict__ bias,
    float* __restrict__ out) {
    // 512 blocks. XCD swizzle: batch b = blockIdx&7 -> all its blocks on one XCD.
    const int b    = blockIdx.x & 7;
    const int pair = blockIdx.x >> 3;          // 0..63, each covers 256 t
    const int wave = threadIdx.x >> 6;         // 0..3
    const int lane = threadIdx.x & 63;
    const int tile = wave >> 1;                // 0..1
    const int half = wave & 1;                 // 0..1
    const int t0   = pair * (2 * TT) + tile * TT;
    const int c    = half * 64 + lane;

    const float* base  = pred + (size_t)b * T * C + c;
    float*       obase = out  + (size_t)b * T * C + c;

    const float rk  = 1.0f / (float)K;
    const float brk = bias[0] * rk;

    const bool interior = (t0 - Pp >= 0) && (t0 + TT + Pp < T);

    float s;
    if (interior) {
        // ---- init: sum rows [t0-250, t0+250], 16 independent accumulators ----
        const float* p = base + (size_t)(t0 - Pp) * C;
        float acc[16];
        #pragma unroll
        for (int u = 0; u < 16; ++u) acc[u] = 0.f;
        int j = 0;
        for (; j + 16 <= K; j += 16) {          // 31 groups of 16
            #pragma unroll
            for (int u = 0; u < 16; ++u)
                acc[u] += p[(size_t)(j + u) * C];
        }
        #pragma unroll
        for (int u = 0; u < K - 496; ++u)       // remainder: 5 rows
            acc[u] += p[(size_t)(j + u) * C];
        #pragma unroll
        for (int w = 8; w >= 1; w >>= 1)
            #pragma unroll
            for (int u = 0; u < w; ++u) acc[u] += acc[u + w];
        s = acc[0];

        // ---- slide, unroll 8 ----
        #pragma unroll 8
        for (int t = t0; t < t0 + TT; ++t) {
            const float cen = base[(size_t)t * C];
            const float nw  = base[(size_t)(t + Pp + 1) * C];
            const float od  = base[(size_t)(t - Pp) * C];
            const float o   = fmaxf(cen, fmaf(s, rk, brk));
            __builtin_nontemporal_store(o, &obase[(size_t)t * C]);
            s += nw - od;
        }
    } else {
        // ---- boundary path with reflection ----
        s = 0.f;
        #pragma unroll 4
        for (int j = t0 - Pp; j <= t0 + Pp; ++j)
            s += base[(size_t)ridx(j) * C];
        #pragma unroll 2
        for (int t = t0; t < t0 + TT; ++t) {
            const float cen = base[(size_t)t * C];
            const float nw  = base[(size_t)ridx(t + Pp + 1) * C];
            const float od  = base[(size_t)ridx(t - Pp) * C];
            const float o   = fmaxf(cen, fmaf(s, rk, brk));
            __builtin_nontemporal_store(o, &obase[(size_t)t * C]);
            s += nw - od;
        }
    }
}

extern "C" void kernel_launch(void* const* d_in, const int* in_sizes, int n_in,
                              void* d_out, int out_size, void* d_ws, size_t ws_size,
                              hipStream_t stream) {
    const float* pred = (const float*)d_in[0];
    const float* bias = (const float*)d_in[1];
    float*       out  = (float*)d_out;

    const int blocks = B * (T / (2 * TT));   // 8 * 64 = 512
    smoother_kernel<<<blocks, BLOCK, 0, stream>>>(pred, bias, out);
}